// Round 17
// baseline (297.122 us; speedup 1.0000x reference)
//
#include <hip/hip_runtime.h>
#include <stdint.h>
#include <math.h>

// Infini-attention forward for MI355X (gfx950).
// Pipeline: wcast4 ; ln3 ; gemm_qkv (one launch, z=0..2) ; stageA ; stageB ; stageC ; gemm_wo
// gemm v7 (frozen): BK=64, 2-deep ring, half-tile staggered staging, counted vmcnt(4),
//   per-phase read|BAR|MFMA separation.
// stageC v7: v5b lockstep/barriers + PER-FRAG s_acc (transient 16 regs, not 64) +
//   DOUBLE-BUFFERED per-wave pl slices [4][2][16][72] (18KB, frags alternate slices so
//   QK->exp->pl->PV chains of consecutive frags overlap; v6's single-slice serialized them).
//   LDS 69->51KB -> 3 blocks/CU if VGPR <=128 (persistent ~112).
// xn_q/xn_k live in d_out (scratch until gemm_wo fully overwrites it -> deterministic).

typedef __attribute__((ext_vector_type(8))) short bf16x8_t;
typedef __attribute__((ext_vector_type(4))) short short4_t;
typedef __attribute__((ext_vector_type(4))) float f32x4;

__device__ __forceinline__ float bf2f(short s){
  union { unsigned u; float f; } v; v.u = ((unsigned)(unsigned short)s) << 16; return v.f;
}
__device__ __forceinline__ short f2bf(float f){
  union { float fl; unsigned u; } v; v.fl = f;
  unsigned r = v.u + 0x7FFFu + ((v.u >> 16) & 1u);   // RNE
  return (short)(unsigned short)(r >> 16);
}
__device__ __forceinline__ f32x4 mfma16(bf16x8_t a, bf16x8_t b, f32x4 c){
  return __builtin_amdgcn_mfma_f32_16x16x32_bf16(a, b, c, 0, 0, 0);
}
__device__ __forceinline__ void gl_lds16(const short* g, short* l){
  __builtin_amdgcn_global_load_lds((const __attribute__((address_space(1))) void*)g,
                                   (__attribute__((address_space(3))) void*)l, 16, 0, 0);
}
__device__ __forceinline__ void bar_pin(){
  __builtin_amdgcn_s_barrier();
  __builtin_amdgcn_sched_barrier(0);
  asm volatile("" ::: "memory");
}

// ---------------- LayerNorm x3: fp32 [16384][1024] -> bf16 ----------------
__global__ __launch_bounds__(256) void ln3(const float* __restrict__ xq, const float* __restrict__ xk,
                                           const float* __restrict__ xv,
                                           const float* __restrict__ gw, const float* __restrict__ gb,
                                           short* __restrict__ oq, short* __restrict__ ok,
                                           short* __restrict__ ov){
  const int row = blockIdx.x, which = blockIdx.y, tid = threadIdx.x;
  const float* x = which == 0 ? xq : which == 1 ? xk : xv;
  short* out     = which == 0 ? oq : which == 1 ? ok : ov;
  const float4 v = *reinterpret_cast<const float4*>(x + (size_t)row*1024 + tid*4);
  float s  = v.x + v.y + v.z + v.w;
  float s2 = v.x*v.x + v.y*v.y + v.z*v.z + v.w*v.w;
  #pragma unroll
  for (int off = 1; off < 64; off <<= 1){
    s  += __shfl_xor(s,  off);
    s2 += __shfl_xor(s2, off);
  }
  __shared__ float red[8];
  if ((tid & 63) == 0){ red[tid>>6] = s; red[4 + (tid>>6)] = s2; }
  __syncthreads();
  s  = red[0] + red[1] + red[2] + red[3];
  s2 = red[4] + red[5] + red[6] + red[7];
  const float mu  = s * (1.0f/1024.0f);
  const float var = s2 * (1.0f/1024.0f) - mu*mu;
  const float rs  = rsqrtf(var + 1e-5f);
  const float4 wv = *reinterpret_cast<const float4*>(gw + tid*4);
  const float4 bv = *reinterpret_cast<const float4*>(gb + tid*4);
  short4_t o;
  o[0] = f2bf((v.x-mu)*rs*wv.x + bv.x);
  o[1] = f2bf((v.y-mu)*rs*wv.y + bv.y);
  o[2] = f2bf((v.z-mu)*rs*wv.z + bv.z);
  o[3] = f2bf((v.w-mu)*rs*wv.w + bv.w);
  *reinterpret_cast<short4_t*>(out + (size_t)row*1024 + tid*4) = o;
}

// ---------------- Weight cast+transpose x4: W[1024][1024] f32 -> Wt[c][k] bf16 ----------------
__global__ __launch_bounds__(256) void wcast4(const float* __restrict__ W0, const float* __restrict__ W1,
                                              const float* __restrict__ W2, const float* __restrict__ W3,
                                              short* __restrict__ T0, short* __restrict__ T1,
                                              short* __restrict__ T2, short* __restrict__ T3){
  const int z = blockIdx.z;
  const float* W = z == 0 ? W0 : z == 1 ? W1 : z == 2 ? W2 : W3;
  short* Wt      = z == 0 ? T0 : z == 1 ? T1 : z == 2 ? T2 : T3;
  __shared__ float tile[64][65];
  const int bx = blockIdx.x, by = blockIdx.y, tid = threadIdx.x;
  #pragma unroll
  for (int p=0;p<4;++p){
    int idx = p*256 + tid;
    int r = idx >> 4, c4 = (idx & 15) << 2;
    const float4 v = *reinterpret_cast<const float4*>(W + (size_t)(by*64 + r)*1024 + bx*64 + c4);
    tile[r][c4+0] = v.x; tile[r][c4+1] = v.y; tile[r][c4+2] = v.z; tile[r][c4+3] = v.w;
  }
  __syncthreads();
  #pragma unroll
  for (int p=0;p<4;++p){
    int idx = p*256 + tid;
    int r = idx >> 4, c4 = (idx & 15) << 2;
    short4_t o;
    o[0] = f2bf(tile[c4+0][r]); o[1] = f2bf(tile[c4+1][r]);
    o[2] = f2bf(tile[c4+2][r]); o[3] = f2bf(tile[c4+3][r]);
    *reinterpret_cast<short4_t*>(Wt + (size_t)(bx*64 + r)*1024 + by*64 + c4) = o;
  }
}

// XCD-chunked remap of 256 (m,c) tiles: XCD k owns m-panels [8k,8k+8) x all 4 c-panels.
__device__ __forceinline__ void remap_mc(int n, int& m0, int& c0){
  int xcd = n & 7, idx = n >> 3;
  m0 = ((xcd << 3) + (idx & 7)) << 8;
  c0 = (idx >> 3) << 8;
}

// ---------------- GEMM body v7: C[16384][1024] = A @ Bt^T (bf16, K=1024) ----------------
__device__ __forceinline__ void gemm_body(short* smem, const short* __restrict__ A,
                                          const short* __restrict__ Bt, void* __restrict__ C,
                                          int mode, int m0, int c0){
  short* As = smem;            // 2 x [256 rows][8 slots][8 shorts]; half0 = rows 0-127
  short* Bs = smem + 32768;
  const int tid = threadIdx.x;
  const int lane = tid & 63, wid = tid >> 6;
  const int wr = wid >> 2, wc = wid & 3;
  const int l15 = lane & 15, lhi = lane >> 4;

  const short* Asrc[4]; const short* Bsrc[4];
  #pragma unroll
  for (int p=0;p<4;++p){
    int i = tid + 512*p;
    int r = i >> 3, g = (i & 7) ^ (r & 7);
    Asrc[p] = A  + (size_t)(m0 + r)*1024 + g*8;
    Bsrc[p] = Bt + (size_t)(c0 + r)*1024 + g*8;
  }

  f32x4 acc[8][4];
  #pragma unroll
  for (int m=0;m<8;++m)
    #pragma unroll
    for (int n=0;n<4;++n) acc[m][n] = (f32x4){0.f,0.f,0.f,0.f};

  #define STAGE_A0(t) { short* _d=&As[((t)&1)<<14]; int _k=(t)<<6; \
      gl_lds16(Asrc[0]+_k, _d+tid*8); gl_lds16(Asrc[1]+_k, _d+4096+tid*8); }
  #define STAGE_A1(t) { short* _d=&As[((t)&1)<<14]; int _k=(t)<<6; \
      gl_lds16(Asrc[2]+_k, _d+8192+tid*8); gl_lds16(Asrc[3]+_k, _d+12288+tid*8); }
  #define STAGE_B0(t) { short* _d=&Bs[((t)&1)<<14]; int _k=(t)<<6; \
      gl_lds16(Bsrc[0]+_k, _d+tid*8); gl_lds16(Bsrc[1]+_k, _d+4096+tid*8); }
  #define STAGE_B1(t) { short* _d=&Bs[((t)&1)<<14]; int _k=(t)<<6; \
      gl_lds16(Bsrc[2]+_k, _d+8192+tid*8); gl_lds16(Bsrc[3]+_k, _d+12288+tid*8); }

  STAGE_B0(0); STAGE_A0(0); STAGE_B1(0); STAGE_A1(0);
  STAGE_B0(1); STAGE_A0(1);
  asm volatile("s_waitcnt vmcnt(4)" ::: "memory");
  bar_pin();

  for (int t = 0; t < 16; ++t){
    const short* Ab = &As[(t & 1) << 14];
    const short* Bb = &Bs[(t & 1) << 14];
    bf16x8_t af[4][2], bfr[4][2];
    // ---- ph1: read A m0-3 + B n0-1 ; stage (t+1)B1 ; BAR ; MFMA m0-3 x n0-1
    #pragma unroll
    for (int m=0;m<4;++m){
      int r = wr*128 + m*16 + l15;
      #pragma unroll
      for (int ks=0;ks<2;++ks){
        int sl = (ks*4 + lhi) ^ (r & 7);
        af[m][ks] = *reinterpret_cast<const bf16x8_t*>(&Ab[r*64 + sl*8]);
      }
    }
    #pragma unroll
    for (int n=0;n<2;++n){
      int r = wc*64 + n*16 + l15;
      #pragma unroll
      for (int ks=0;ks<2;++ks){
        int sl = (ks*4 + lhi) ^ (r & 7);
        bfr[n][ks] = *reinterpret_cast<const bf16x8_t*>(&Bb[r*64 + sl*8]);
      }
    }
    if (t < 15) STAGE_B1(t+1);
    bar_pin();
    __builtin_amdgcn_s_setprio(1);
    #pragma unroll
    for (int m=0;m<4;++m)
      #pragma unroll
      for (int n=0;n<2;++n)
        #pragma unroll
        for (int ks=0;ks<2;++ks)
          acc[m][n] = mfma16(af[m][ks], bfr[n][ks], acc[m][n]);
    __builtin_amdgcn_s_setprio(0);
    // ---- ph2: read B n2-3 ; stage (t+1)A1 ; BAR ; MFMA m0-3 x n2-3
    #pragma unroll
    for (int n=2;n<4;++n){
      int r = wc*64 + n*16 + l15;
      #pragma unroll
      for (int ks=0;ks<2;++ks){
        int sl = (ks*4 + lhi) ^ (r & 7);
        bfr[n][ks] = *reinterpret_cast<const bf16x8_t*>(&Bb[r*64 + sl*8]);
      }
    }
    if (t < 15) STAGE_A1(t+1);
    bar_pin();
    __builtin_amdgcn_s_setprio(1);
    #pragma unroll
    for (int m=0;m<4;++m)
      #pragma unroll
      for (int n=2;n<4;++n)
        #pragma unroll
        for (int ks=0;ks<2;++ks)
          acc[m][n] = mfma16(af[m][ks], bfr[n][ks], acc[m][n]);
    __builtin_amdgcn_s_setprio(0);
    asm volatile("" ::: "memory");
    bar_pin();                        // B(t) consumed -> B0 region reusable
    // ---- ph3: read A m4-7 ; stage (t+2)B0 ; BAR ; MFMA m4-7 x n0-1
    #pragma unroll
    for (int m=0;m<4;++m){
      int r = wr*128 + 64 + m*16 + l15;
      #pragma unroll
      for (int ks=0;ks<2;++ks){
        int sl = (ks*4 + lhi) ^ (r & 7);
        af[m][ks] = *reinterpret_cast<const bf16x8_t*>(&Ab[r*64 + sl*8]);
      }
    }
    if (t < 14) STAGE_B0(t+2);
    bar_pin();
    __builtin_amdgcn_s_setprio(1);
    #pragma unroll
    for (int m=0;m<4;++m)
      #pragma unroll
      for (int n=0;n<2;++n)
        #pragma unroll
        for (int ks=0;ks<2;++ks)
          acc[4+m][n] = mfma16(af[m][ks], bfr[n][ks], acc[4+m][n]);
    __builtin_amdgcn_s_setprio(0);
    asm volatile("" ::: "memory");
    bar_pin();                        // A(t) consumed -> A0 region reusable
    // ---- ph4: stage (t+2)A0 ; MFMA m4-7 x n2-3 ; counted wait ; barrier
    if (t < 14) STAGE_A0(t+2);
    __builtin_amdgcn_s_setprio(1);
    #pragma unroll
    for (int m=0;m<4;++m)
      #pragma unroll
      for (int n=2;n<4;++n)
        #pragma unroll
        for (int ks=0;ks<2;++ks)
          acc[4+m][n] = mfma16(af[m][ks], bfr[n][ks], acc[4+m][n]);
    __builtin_amdgcn_s_setprio(0);
    if (t < 14)       { asm volatile("s_waitcnt vmcnt(4)" ::: "memory"); }
    else if (t == 14) { asm volatile("s_waitcnt vmcnt(0)" ::: "memory"); }
    if (t < 15) bar_pin();
  }
  #undef STAGE_A0
  #undef STAGE_A1
  #undef STAGE_B0
  #undef STAGE_B1

  if (mode == 0){
    short* Cb = (short*)C;
    #pragma unroll
    for (int m=0;m<8;++m)
      #pragma unroll
      for (int n=0;n<4;++n)
        #pragma unroll
        for (int j=0;j<4;++j){
          int row = m0 + wr*128 + m*16 + lhi*4 + j;
          int col = c0 + wc*64 + n*16 + l15;
          size_t oidx = ((size_t)((row>>12)*16 + (col>>6)) * 4096 + (size_t)(row & 4095)) * 64 + (col & 63);
          Cb[oidx] = f2bf(acc[m][n][j]);
        }
  } else if (mode == 2){
    short* Cb = (short*)C;
    #pragma unroll
    for (int m=0;m<8;++m)
      #pragma unroll
      for (int n=0;n<4;++n){
        int rowb = m0 + wr*128 + m*16 + lhi*4;
        int col  = c0 + wc*64 + n*16 + l15;
        int nh = ((rowb>>12)<<4) + (col>>6);
        int e  = col & 63;
        int tt = rowb & 4095;
        short4_t o;
        #pragma unroll
        for (int j=0;j<4;++j) o[j] = f2bf(acc[m][n][j]);
        *reinterpret_cast<short4_t*>(&Cb[((size_t)nh*64 + e)*4096 + tt]) = o;
      }
  } else {
    float* Cf = (float*)C;
    #pragma unroll
    for (int m=0;m<8;++m)
      #pragma unroll
      for (int n=0;n<4;++n)
        #pragma unroll
        for (int j=0;j<4;++j){
          int row = m0 + wr*128 + m*16 + lhi*4 + j;
          int col = c0 + wc*64 + n*16 + l15;
          Cf[(size_t)row*1024 + col] = acc[m][n][j];
        }
  }
}

// All 3 projection GEMMs in one launch: z=0 Q(mode0), z=1 K(mode0), z=2 V(mode2).
__global__ __launch_bounds__(512, 2) void gemm_qkv(const short* __restrict__ A0, const short* __restrict__ A1,
    const short* __restrict__ A2, const short* __restrict__ B0, const short* __restrict__ B1,
    const short* __restrict__ B2, short* __restrict__ C0, short* __restrict__ C1, short* __restrict__ C2){
  extern __shared__ short smem[];
  const int z = blockIdx.z;
  const short* A = z == 0 ? A0 : z == 1 ? A1 : A2;
  const short* B = z == 0 ? B0 : z == 1 ? B1 : B2;
  short* C       = z == 0 ? C0 : z == 1 ? C1 : C2;
  int m0, c0; remap_mc(blockIdx.x + 64*blockIdx.y, m0, c0);
  gemm_body(smem, A, B, (void*)C, z == 2 ? 2 : 0, m0, c0);
}

__global__ __launch_bounds__(512, 2) void gemm_wo(const short* __restrict__ A, const short* __restrict__ Bt,
                                                  float* __restrict__ C){
  extern __shared__ short smem[];
  int m0, c0; remap_mc(blockIdx.x + 64*blockIdx.y, m0, c0);
  gemm_body(smem, A, Bt, (void*)C, 1, m0, c0);
}

// ---------------- Stage A: delta^T[e][d] = sum_s vs[s][e]*sk[s][d] via MFMA ----------------
__global__ __launch_bounds__(256) void stageA(const short* __restrict__ kh, const short* __restrict__ vhT,
                                              short* __restrict__ delta_b, float* __restrict__ zd){
  const int seg = blockIdx.x, nh = blockIdx.y, tid = threadIdx.x;
  const int lane = tid & 63, w = tid >> 6;
  const int l15 = lane & 15, lhi = lane >> 4;
  __shared__ short skT[64*256];      // element (d,s) at byte ((d*256+s)*2) ^ (((d>>3)&7)<<4)
  const size_t thead = (size_t)nh*4096 + (size_t)seg*256;

  #pragma unroll
  for (int ch=0; ch<8; ++ch){
    int s  = ch*32 + (tid>>3);
    int lc = (tid&7)*8;
    bf16x8_t kv = *reinterpret_cast<const bf16x8_t*>(kh + (thead + s)*64 + lc);
    #pragma unroll
    for (int j=0;j<8;++j){
      float f = bf2f(kv[j]);
      short sv = f2bf((f > 0.f) ? (f + 1.f) : __expf(f));   // elu(k)+1
      int d = lc + j;
      int bo = ((d*256 + s) << 1) ^ (((d>>3)&7) << 4);
      *reinterpret_cast<short*>(reinterpret_cast<char*>(skT) + bo) = sv;
    }
  }
  __syncthreads();

  bf16x8_t ones;
  #pragma unroll
  for (int i=0;i<8;++i) ones[i] = (short)0x3F80;

  f32x4 dacc[4], zacc[4];
  #pragma unroll
  for (int jf=0;jf<4;++jf){ dacc[jf] = (f32x4){0.f,0.f,0.f,0.f}; zacc[jf] = (f32x4){0.f,0.f,0.f,0.f}; }

  #pragma unroll
  for (int ks=0; ks<8; ++ks){
    bf16x8_t av = *reinterpret_cast<const bf16x8_t*>(
        vhT + ((size_t)nh*64 + w*16 + l15)*4096 + (size_t)seg*256 + ks*32 + lhi*8);
    #pragma unroll
    for (int jf=0;jf<4;++jf){
      int d  = jf*16 + l15;
      int so = ks*32 + lhi*8;
      int bo = ((d*256 + so) << 1) ^ (((d>>3)&7) << 4);
      bf16x8_t bk = *reinterpret_cast<const bf16x8_t*>(reinterpret_cast<char*>(skT) + bo);
      dacc[jf] = mfma16(av, bk, dacc[jf]);
      if (w == 0) zacc[jf] = mfma16(ones, bk, zacc[jf]);
    }
  }

  short* dp = delta_b + (size_t)(seg*64 + nh)*4096;
  #pragma unroll
  for (int jf=0;jf<4;++jf)
    #pragma unroll
    for (int j=0;j<4;++j)
      dp[(w*16 + lhi*4 + j)*64 + jf*16 + l15] = f2bf(dacc[jf][j]);
  if (w == 0 && lhi == 0){
    #pragma unroll
    for (int jf=0;jf<4;++jf)
      zd[(size_t)(seg*64 + nh)*64 + jf*16 + l15] = zacc[jf][0];
  }
}

// ---------------- Stage B: exclusive prefix over the 16 segments (bf16 out) ----------------
__global__ __launch_bounds__(256) void stageB(const short* __restrict__ delta_b, const float* __restrict__ zd,
                                              short* __restrict__ mpre_b, float* __restrict__ zpre){
  const int c = blockIdx.x, nh = blockIdx.y, tid = threadIdx.x;
  const int idx = c*256 + tid;
  float acc = 0.f;
  for (int seg=0; seg<16; ++seg){
    size_t b = (size_t)(seg*64 + nh)*4096 + idx;
    mpre_b[b] = f2bf(acc);
    acc += bf2f(delta_b[b]);
  }
  if (c == 0 && tid < 64){
    float za = 0.f;
    for (int seg=0; seg<16; ++seg){
      size_t zb = (size_t)(seg*64 + nh)*64 + tid;
      zpre[zb] = za;
      za += zd[zb];
    }
  }
}

// ---------------- Stage C v7: balanced lockstep attention + retrieval, per-frag chains ----
// 1024 blocks (16 seg x 64 nh), 4 waves. Wave w owns 16-row frags at q-rows m*64+w*16, m=0..3.
// At kt, every wave computes frags m>=kt (balanced). K/V 2-deep LDS ring (stage at kt top,
// race-fix barrier tail at kt end). Per-frag s_acc (16 transient regs); pl double-buffered
// slices [wave][m&1][16][72] so consecutive frags' QK->exp->pl->PV chains overlap.
__global__ __launch_bounds__(256) void stageC(const short* __restrict__ qh, const short* __restrict__ kh,
    const short* __restrict__ vhT, const short* __restrict__ mpre_b, const float* __restrict__ z_pre,
    const float* __restrict__ beta, short* __restrict__ seqs)
{
  const int seg  = blockIdx.x;
  const int nh   = blockIdx.y;
  const int tid = threadIdx.x;
  const int lane = tid & 63, w = tid >> 6;
  const int l15 = lane & 15, lhi = lane >> 4;

  __shared__ short Ks[2][4096];      // K tile [64 t'][8 slots x 8], slot = chunk ^ (r&7)
  __shared__ short Vs[2][4096];      // V^T tile [64 e][8 slots x 8], same swizzle
  __shared__ float zl[64];
  __shared__ short pl[4][2][16][72]; // per-wave double-buffered P slices (18KB)

  const size_t thead = (size_t)nh*4096 + (size_t)seg*256;

  const short* Ksrc[2]; const short* Vsrc[2];
  #pragma unroll
  for (int p=0;p<2;++p){
    int i = tid + 256*p, r = i >> 3, g = (i & 7) ^ (r & 7);
    Ksrc[p] = kh + (thead + r)*64 + g*8;                                    // + kt*4096
    Vsrc[p] = vhT + ((size_t)nh*64 + r)*4096 + (size_t)seg*256 + g*8;       // + kt*64
  }
  #define STAGE_KV(kt) { short* _kd = Ks[(kt)&1]; short* _vd = Vs[(kt)&1]; \
      gl_lds16(Ksrc[0] + (kt)*4096, _kd + tid*8); \
      gl_lds16(Ksrc[1] + (kt)*4096, _kd + 2048 + tid*8); \
      gl_lds16(Vsrc[0] + (kt)*64,  _vd + tid*8); \
      gl_lds16(Vsrc[1] + (kt)*64,  _vd + 2048 + tid*8); }

  if (tid < 64) zl[tid] = z_pre[(size_t)(seg*64 + nh)*64 + tid];

  // frag m covers q-rows m*64 + w*16 + [0,16)
  bf16x8_t aq[4][2];
  #pragma unroll
  for (int m=0;m<4;++m)
    #pragma unroll
    for (int ks=0;ks<2;++ks)
      aq[m][ks] = *reinterpret_cast<const bf16x8_t*>(qh + (thead + m*64 + w*16 + l15)*64 + ks*32 + lhi*8);

  STAGE_KV(0);
  asm volatile("s_waitcnt vmcnt(0)" ::: "memory");
  __syncthreads();

  const float bg = 1.f / (1.f + __expf(-beta[0]));
  const float scale = 0.125f;
  bf16x8_t ones;
  #pragma unroll
  for (int i=0;i<8;++i) ones[i] = (short)0x3F80;

  f32x4 o_acc[4][4], l_acc[4];
  #pragma unroll
  for (int m=0;m<4;++m){
    l_acc[m] = (f32x4){0.f,0.f,0.f,0.f};
    #pragma unroll
    for (int jf=0;jf<4;++jf) o_acc[m][jf] = (f32x4){0.f,0.f,0.f,0.f};
  }

  #pragma unroll
  for (int kt = 0; kt < 4; ++kt){
    const short* Kb = Ks[kt & 1];
    const short* Vb = Vs[kt & 1];
    if (kt < 3) STAGE_KV(kt+1);
    #pragma unroll
    for (int m=0;m<4;++m){
      if (m < kt) continue;              // fully masked: no contribution
      short* pls = &pl[w][m & 1][0][0];  // alternate slices -> chains overlap
      f32x4 s_acc[4];
      #pragma unroll
      for (int jf=0;jf<4;++jf) s_acc[jf] = (f32x4){0.f,0.f,0.f,0.f};
      #pragma unroll
      for (int ks=0;ks<2;++ks){
        #pragma unroll
        for (int jf=0;jf<4;++jf){
          int r = jf*16 + l15;
          int sl = (ks*4 + lhi) ^ (r & 7);
          bf16x8_t bk = *reinterpret_cast<const bf16x8_t*>(&Kb[r*64 + sl*8]);
          s_acc[jf] = mfma16(aq[m][ks], bk, s_acc[jf]);
        }
      }
      #pragma unroll
      for (int jf=0;jf<4;++jf)
        #pragma unroll
        for (int j=0;j<4;++j){
          float vv = s_acc[jf][j] * scale;
          if (m == kt){
            int sr = w*16 + lhi*4 + j;     // local row within the 64-block
            int tc = jf*16 + l15;          // local col
            if (tc > sr) vv = -INFINITY;
          }
          float pv = __expf(vv);
          pls[(lhi*4 + j)*72 + jf*16 + l15] = f2bf(pv);
        }
      #pragma unroll
      for (int ks2=0;ks2<2;++ks2){
        bf16x8_t ap = *reinterpret_cast<const bf16x8_t*>(&pls[l15*72 + ks2*32 + lhi*8]);
        l_acc[m] = mfma16(ap, ones, l_acc[m]);
        #pragma unroll
        for (int jf=0;jf<4;++jf){
          int e = jf*16 + l15;
          int sl = (ks2*4 + lhi) ^ (e & 7);
          bf16x8_t bv = *reinterpret_cast<const bf16x8_t*>(&Vb[e*64 + sl*8]);
          o_acc[m][jf] = mfma16(ap, bv, o_acc[m][jf]);
        }
      }
    }
    if (kt < 3){
      // race-fix tail: vmcnt drain + barrier + full pin (s_barrier is not an IR memory fence)
      asm volatile("s_waitcnt vmcnt(0)" ::: "memory");
      __builtin_amdgcn_s_barrier();
      __builtin_amdgcn_sched_barrier(0);
      asm volatile("" ::: "memory");
    }
  }
  #undef STAGE_KV

  // retrieval: num = (elu(q)+1) @ mem ; den = (elu(q)+1) . z
  bf16x8_t sq[4][2];
  #pragma unroll
  for (int m=0;m<4;++m)
    #pragma unroll
    for (int ks=0;ks<2;++ks)
      #pragma unroll
      for (int i=0;i<8;++i){
        float f = bf2f(aq[m][ks][i]);
        sq[m][ks][i] = f2bf((f > 0.f) ? (f + 1.f) : __expf(f));
      }
  bf16x8_t bz[2];
  #pragma unroll
  for (int ks=0;ks<2;++ks)
    #pragma unroll
    for (int i=0;i<8;++i) bz[ks][i] = f2bf(zl[ks*32 + lhi*8 + i]);

  const short* mpbase = mpre_b + (size_t)(seg*64 + nh)*4096;
  f32x4 n_acc[4][4], d_acc[4];
  #pragma unroll
  for (int m=0;m<4;++m){
    d_acc[m] = (f32x4){0.f,0.f,0.f,0.f};
    #pragma unroll
    for (int jf=0;jf<4;++jf) n_acc[m][jf] = (f32x4){0.f,0.f,0.f,0.f};
  }
  #pragma unroll
  for (int ks=0;ks<2;++ks){
    bf16x8_t bm[4];
    #pragma unroll
    for (int jf=0;jf<4;++jf)
      bm[jf] = *reinterpret_cast<const bf16x8_t*>(mpbase + (jf*16 + l15)*64 + ks*32 + lhi*8);
    #pragma unroll
    for (int m=0;m<4;++m){
      #pragma unroll
      for (int jf=0;jf<4;++jf) n_acc[m][jf] = mfma16(sq[m][ks], bm[jf], n_acc[m][jf]);
      d_acc[m] = mfma16(sq[m][ks], bz[ks], d_acc[m]);
    }
  }

  const int nb = nh >> 4, hh = nh & 15;
  #pragma unroll
  for (int m=0;m<4;++m)
    #pragma unroll
    for (int jf=0;jf<4;++jf)
      #pragma unroll
      for (int j=0;j<4;++j){
        float attn = o_acc[m][jf][j] / l_acc[m][j];
        float amem = n_acc[m][jf][j] / (d_acc[m][j] + 1e-6f);
        float ov = bg*amem + (1.f-bg)*attn;
        int srow = m*64 + w*16 + lhi*4 + j;
        seqs[((size_t)nb*4096 + (size_t)seg*256 + srow)*1024 + hh*64 + jf*16 + l15] = f2bf(ov);
      }
}

// ---------------- launch ----------------
extern "C" void kernel_launch(void* const* d_in, const int* in_sizes, int n_in,
                              void* d_out, int out_size, void* d_ws, size_t ws_size,
                              hipStream_t stream){
  (void)in_sizes; (void)n_in; (void)out_size; (void)ws_size;
  const float* q    = (const float*)d_in[0];
  const float* k    = (const float*)d_in[1];
  const float* v    = (const float*)d_in[2];
  const float* Wq   = (const float*)d_in[3];
  const float* Wk   = (const float*)d_in[4];
  const float* Wv   = (const float*)d_in[5];
  const float* Wo   = (const float*)d_in[6];
  const float* lnw  = (const float*)d_in[7];
  const float* lnb  = (const float*)d_in[8];
  const float* beta = (const float*)d_in[9];
  char* ws = (char*)d_ws;
  const size_t MB = 1024ull*1024ull;
  short* WqT    = (short*)(ws + 0*MB);
  short* WkT    = (short*)(ws + 2*MB);
  short* WvT    = (short*)(ws + 4*MB);
  short* WoT    = (short*)(ws + 6*MB);
  short* xn_v   = (short*)(ws + 8*MB);    // 32MB; reused as seqs after projections
  short* seqs   = xn_v;
  short* qh     = (short*)(ws + 40*MB);   // [nh][t][64]
  short* kh     = (short*)(ws + 72*MB);   // [nh][t][64]
  short* vhT    = (short*)(ws + 104*MB);  // [nh][e][t]
  short* delta_b= (short*)(ws + 136*MB);  // bf16 [16][64][e*64+d], 8MB
  float* zd     = (float*)(ws + 144*MB);  // 256KB
  short* mpre_b = (short*)(ws + 145*MB);  // bf16, 8MB
  float* zpre   = (float*)(ws + 153*MB);  // 256KB
  // d_out (16384*1024 f32 = 64MB) used as scratch for two bf16 LN outputs (2x32MB),
  // fully overwritten by gemm_wo at the end -> deterministic.
  short* xn_q   = (short*)d_out;
  short* xn_k   = (short*)d_out + 16384ull*1024ull;

  wcast4<<<dim3(16,16,4),256,0,stream>>>(Wq,Wk,Wv,Wo, WqT,WkT,WvT,WoT);
  ln3<<<dim3(16384,3),256,0,stream>>>(q,k,v, lnw,lnb, xn_q,xn_k,xn_v);

  const size_t lds_gemm = 131072;
  gemm_qkv<<<dim3(64,4,3),512,lds_gemm,stream>>>(xn_q,xn_k,xn_v, WqT,WkT,WvT, qh,kh,vhT);

  stageA<<<dim3(16,64),256,0,stream>>>(kh, vhT, delta_b, zd);
  stageB<<<dim3(16,64),256,0,stream>>>(delta_b, zd, mpre_b, zpre);
  stageC<<<dim3(16,64),256,0,stream>>>(qh, kh, vhT, mpre_b, zpre, beta, seqs);
  gemm_wo<<<dim3(64,4),512,lds_gemm,stream>>>(seqs, WoT, (float*)d_out);
}

// Round 18
// 293.130 us; speedup vs baseline: 1.0136x; 1.0136x over previous
//
#include <hip/hip_runtime.h>
#include <stdint.h>
#include <math.h>

// Infini-attention forward for MI355X (gfx950). FINAL = best-measured config (round 16).
// Pipeline: wcast4 ; ln3 ; gemm_qkv (one launch, z=0..2) ; stageA ; stageB ; stageC ; gemm_wo
// gemm v7: BK=64, 2-deep ring, half-tile staggered staging, counted vmcnt(4),
//   per-phase read|BAR|MFMA separation, XCD-chunked block remap, 8-slot XOR swizzle (0 conflicts).
// stageC v5b: lockstep kt, interleaved row ownership (wave w owns frags at q-rows m*64+w*16;
//   at kt all waves compute frags m>=kt -> balanced), race-fix barrier tails.
// xn_q/xn_k live in d_out (scratch until gemm_wo fully overwrites it -> deterministic).

typedef __attribute__((ext_vector_type(8))) short bf16x8_t;
typedef __attribute__((ext_vector_type(4))) short short4_t;
typedef __attribute__((ext_vector_type(4))) float f32x4;

__device__ __forceinline__ float bf2f(short s){
  union { unsigned u; float f; } v; v.u = ((unsigned)(unsigned short)s) << 16; return v.f;
}
__device__ __forceinline__ short f2bf(float f){
  union { float fl; unsigned u; } v; v.fl = f;
  unsigned r = v.u + 0x7FFFu + ((v.u >> 16) & 1u);   // RNE
  return (short)(unsigned short)(r >> 16);
}
__device__ __forceinline__ f32x4 mfma16(bf16x8_t a, bf16x8_t b, f32x4 c){
  return __builtin_amdgcn_mfma_f32_16x16x32_bf16(a, b, c, 0, 0, 0);
}
__device__ __forceinline__ void gl_lds16(const short* g, short* l){
  __builtin_amdgcn_global_load_lds((const __attribute__((address_space(1))) void*)g,
                                   (__attribute__((address_space(3))) void*)l, 16, 0, 0);
}
__device__ __forceinline__ void bar_pin(){
  __builtin_amdgcn_s_barrier();
  __builtin_amdgcn_sched_barrier(0);
  asm volatile("" ::: "memory");
}

// ---------------- LayerNorm x3: fp32 [16384][1024] -> bf16 ----------------
__global__ __launch_bounds__(256) void ln3(const float* __restrict__ xq, const float* __restrict__ xk,
                                           const float* __restrict__ xv,
                                           const float* __restrict__ gw, const float* __restrict__ gb,
                                           short* __restrict__ oq, short* __restrict__ ok,
                                           short* __restrict__ ov){
  const int row = blockIdx.x, which = blockIdx.y, tid = threadIdx.x;
  const float* x = which == 0 ? xq : which == 1 ? xk : xv;
  short* out     = which == 0 ? oq : which == 1 ? ok : ov;
  const float4 v = *reinterpret_cast<const float4*>(x + (size_t)row*1024 + tid*4);
  float s  = v.x + v.y + v.z + v.w;
  float s2 = v.x*v.x + v.y*v.y + v.z*v.z + v.w*v.w;
  #pragma unroll
  for (int off = 1; off < 64; off <<= 1){
    s  += __shfl_xor(s,  off);
    s2 += __shfl_xor(s2, off);
  }
  __shared__ float red[8];
  if ((tid & 63) == 0){ red[tid>>6] = s; red[4 + (tid>>6)] = s2; }
  __syncthreads();
  s  = red[0] + red[1] + red[2] + red[3];
  s2 = red[4] + red[5] + red[6] + red[7];
  const float mu  = s * (1.0f/1024.0f);
  const float var = s2 * (1.0f/1024.0f) - mu*mu;
  const float rs  = rsqrtf(var + 1e-5f);
  const float4 wv = *reinterpret_cast<const float4*>(gw + tid*4);
  const float4 bv = *reinterpret_cast<const float4*>(gb + tid*4);
  short4_t o;
  o[0] = f2bf((v.x-mu)*rs*wv.x + bv.x);
  o[1] = f2bf((v.y-mu)*rs*wv.y + bv.y);
  o[2] = f2bf((v.z-mu)*rs*wv.z + bv.z);
  o[3] = f2bf((v.w-mu)*rs*wv.w + bv.w);
  *reinterpret_cast<short4_t*>(out + (size_t)row*1024 + tid*4) = o;
}

// ---------------- Weight cast+transpose x4: W[1024][1024] f32 -> Wt[c][k] bf16 ----------------
__global__ __launch_bounds__(256) void wcast4(const float* __restrict__ W0, const float* __restrict__ W1,
                                              const float* __restrict__ W2, const float* __restrict__ W3,
                                              short* __restrict__ T0, short* __restrict__ T1,
                                              short* __restrict__ T2, short* __restrict__ T3){
  const int z = blockIdx.z;
  const float* W = z == 0 ? W0 : z == 1 ? W1 : z == 2 ? W2 : W3;
  short* Wt      = z == 0 ? T0 : z == 1 ? T1 : z == 2 ? T2 : T3;
  __shared__ float tile[64][65];
  const int bx = blockIdx.x, by = blockIdx.y, tid = threadIdx.x;
  #pragma unroll
  for (int p=0;p<4;++p){
    int idx = p*256 + tid;
    int r = idx >> 4, c4 = (idx & 15) << 2;
    const float4 v = *reinterpret_cast<const float4*>(W + (size_t)(by*64 + r)*1024 + bx*64 + c4);
    tile[r][c4+0] = v.x; tile[r][c4+1] = v.y; tile[r][c4+2] = v.z; tile[r][c4+3] = v.w;
  }
  __syncthreads();
  #pragma unroll
  for (int p=0;p<4;++p){
    int idx = p*256 + tid;
    int r = idx >> 4, c4 = (idx & 15) << 2;
    short4_t o;
    o[0] = f2bf(tile[c4+0][r]); o[1] = f2bf(tile[c4+1][r]);
    o[2] = f2bf(tile[c4+2][r]); o[3] = f2bf(tile[c4+3][r]);
    *reinterpret_cast<short4_t*>(Wt + (size_t)(bx*64 + r)*1024 + by*64 + c4) = o;
  }
}

// XCD-chunked remap of 256 (m,c) tiles: XCD k owns m-panels [8k,8k+8) x all 4 c-panels.
__device__ __forceinline__ void remap_mc(int n, int& m0, int& c0){
  int xcd = n & 7, idx = n >> 3;
  m0 = ((xcd << 3) + (idx & 7)) << 8;
  c0 = (idx >> 3) << 8;
}

// ---------------- GEMM body v7: C[16384][1024] = A @ Bt^T (bf16, K=1024) ----------------
__device__ __forceinline__ void gemm_body(short* smem, const short* __restrict__ A,
                                          const short* __restrict__ Bt, void* __restrict__ C,
                                          int mode, int m0, int c0){
  short* As = smem;            // 2 x [256 rows][8 slots][8 shorts]; half0 = rows 0-127
  short* Bs = smem + 32768;
  const int tid = threadIdx.x;
  const int lane = tid & 63, wid = tid >> 6;
  const int wr = wid >> 2, wc = wid & 3;
  const int l15 = lane & 15, lhi = lane >> 4;

  const short* Asrc[4]; const short* Bsrc[4];
  #pragma unroll
  for (int p=0;p<4;++p){
    int i = tid + 512*p;
    int r = i >> 3, g = (i & 7) ^ (r & 7);
    Asrc[p] = A  + (size_t)(m0 + r)*1024 + g*8;
    Bsrc[p] = Bt + (size_t)(c0 + r)*1024 + g*8;
  }

  f32x4 acc[8][4];
  #pragma unroll
  for (int m=0;m<8;++m)
    #pragma unroll
    for (int n=0;n<4;++n) acc[m][n] = (f32x4){0.f,0.f,0.f,0.f};

  #define STAGE_A0(t) { short* _d=&As[((t)&1)<<14]; int _k=(t)<<6; \
      gl_lds16(Asrc[0]+_k, _d+tid*8); gl_lds16(Asrc[1]+_k, _d+4096+tid*8); }
  #define STAGE_A1(t) { short* _d=&As[((t)&1)<<14]; int _k=(t)<<6; \
      gl_lds16(Asrc[2]+_k, _d+8192+tid*8); gl_lds16(Asrc[3]+_k, _d+12288+tid*8); }
  #define STAGE_B0(t) { short* _d=&Bs[((t)&1)<<14]; int _k=(t)<<6; \
      gl_lds16(Bsrc[0]+_k, _d+tid*8); gl_lds16(Bsrc[1]+_k, _d+4096+tid*8); }
  #define STAGE_B1(t) { short* _d=&Bs[((t)&1)<<14]; int _k=(t)<<6; \
      gl_lds16(Bsrc[2]+_k, _d+8192+tid*8); gl_lds16(Bsrc[3]+_k, _d+12288+tid*8); }

  STAGE_B0(0); STAGE_A0(0); STAGE_B1(0); STAGE_A1(0);
  STAGE_B0(1); STAGE_A0(1);
  asm volatile("s_waitcnt vmcnt(4)" ::: "memory");
  bar_pin();

  for (int t = 0; t < 16; ++t){
    const short* Ab = &As[(t & 1) << 14];
    const short* Bb = &Bs[(t & 1) << 14];
    bf16x8_t af[4][2], bfr[4][2];
    // ---- ph1: read A m0-3 + B n0-1 ; stage (t+1)B1 ; BAR ; MFMA m0-3 x n0-1
    #pragma unroll
    for (int m=0;m<4;++m){
      int r = wr*128 + m*16 + l15;
      #pragma unroll
      for (int ks=0;ks<2;++ks){
        int sl = (ks*4 + lhi) ^ (r & 7);
        af[m][ks] = *reinterpret_cast<const bf16x8_t*>(&Ab[r*64 + sl*8]);
      }
    }
    #pragma unroll
    for (int n=0;n<2;++n){
      int r = wc*64 + n*16 + l15;
      #pragma unroll
      for (int ks=0;ks<2;++ks){
        int sl = (ks*4 + lhi) ^ (r & 7);
        bfr[n][ks] = *reinterpret_cast<const bf16x8_t*>(&Bb[r*64 + sl*8]);
      }
    }
    if (t < 15) STAGE_B1(t+1);
    bar_pin();
    __builtin_amdgcn_s_setprio(1);
    #pragma unroll
    for (int m=0;m<4;++m)
      #pragma unroll
      for (int n=0;n<2;++n)
        #pragma unroll
        for (int ks=0;ks<2;++ks)
          acc[m][n] = mfma16(af[m][ks], bfr[n][ks], acc[m][n]);
    __builtin_amdgcn_s_setprio(0);
    // ---- ph2: read B n2-3 ; stage (t+1)A1 ; BAR ; MFMA m0-3 x n2-3
    #pragma unroll
    for (int n=2;n<4;++n){
      int r = wc*64 + n*16 + l15;
      #pragma unroll
      for (int ks=0;ks<2;++ks){
        int sl = (ks*4 + lhi) ^ (r & 7);
        bfr[n][ks] = *reinterpret_cast<const bf16x8_t*>(&Bb[r*64 + sl*8]);
      }
    }
    if (t < 15) STAGE_A1(t+1);
    bar_pin();
    __builtin_amdgcn_s_setprio(1);
    #pragma unroll
    for (int m=0;m<4;++m)
      #pragma unroll
      for (int n=2;n<4;++n)
        #pragma unroll
        for (int ks=0;ks<2;++ks)
          acc[m][n] = mfma16(af[m][ks], bfr[n][ks], acc[m][n]);
    __builtin_amdgcn_s_setprio(0);
    asm volatile("" ::: "memory");
    bar_pin();                        // B(t) consumed -> B0 region reusable
    // ---- ph3: read A m4-7 ; stage (t+2)B0 ; BAR ; MFMA m4-7 x n0-1
    #pragma unroll
    for (int m=0;m<4;++m){
      int r = wr*128 + 64 + m*16 + l15;
      #pragma unroll
      for (int ks=0;ks<2;++ks){
        int sl = (ks*4 + lhi) ^ (r & 7);
        af[m][ks] = *reinterpret_cast<const bf16x8_t*>(&Ab[r*64 + sl*8]);
      }
    }
    if (t < 14) STAGE_B0(t+2);
    bar_pin();
    __builtin_amdgcn_s_setprio(1);
    #pragma unroll
    for (int m=0;m<4;++m)
      #pragma unroll
      for (int n=0;n<2;++n)
        #pragma unroll
        for (int ks=0;ks<2;++ks)
          acc[4+m][n] = mfma16(af[m][ks], bfr[n][ks], acc[4+m][n]);
    __builtin_amdgcn_s_setprio(0);
    asm volatile("" ::: "memory");
    bar_pin();                        // A(t) consumed -> A0 region reusable
    // ---- ph4: stage (t+2)A0 ; MFMA m4-7 x n2-3 ; counted wait ; barrier
    if (t < 14) STAGE_A0(t+2);
    __builtin_amdgcn_s_setprio(1);
    #pragma unroll
    for (int m=0;m<4;++m)
      #pragma unroll
      for (int n=2;n<4;++n)
        #pragma unroll
        for (int ks=0;ks<2;++ks)
          acc[4+m][n] = mfma16(af[m][ks], bfr[n][ks], acc[4+m][n]);
    __builtin_amdgcn_s_setprio(0);
    if (t < 14)       { asm volatile("s_waitcnt vmcnt(4)" ::: "memory"); }
    else if (t == 14) { asm volatile("s_waitcnt vmcnt(0)" ::: "memory"); }
    if (t < 15) bar_pin();
  }
  #undef STAGE_A0
  #undef STAGE_A1
  #undef STAGE_B0
  #undef STAGE_B1

  if (mode == 0){
    short* Cb = (short*)C;
    #pragma unroll
    for (int m=0;m<8;++m)
      #pragma unroll
      for (int n=0;n<4;++n)
        #pragma unroll
        for (int j=0;j<4;++j){
          int row = m0 + wr*128 + m*16 + lhi*4 + j;
          int col = c0 + wc*64 + n*16 + l15;
          size_t oidx = ((size_t)((row>>12)*16 + (col>>6)) * 4096 + (size_t)(row & 4095)) * 64 + (col & 63);
          Cb[oidx] = f2bf(acc[m][n][j]);
        }
  } else if (mode == 2){
    short* Cb = (short*)C;
    #pragma unroll
    for (int m=0;m<8;++m)
      #pragma unroll
      for (int n=0;n<4;++n){
        int rowb = m0 + wr*128 + m*16 + lhi*4;
        int col  = c0 + wc*64 + n*16 + l15;
        int nh = ((rowb>>12)<<4) + (col>>6);
        int e  = col & 63;
        int tt = rowb & 4095;
        short4_t o;
        #pragma unroll
        for (int j=0;j<4;++j) o[j] = f2bf(acc[m][n][j]);
        *reinterpret_cast<short4_t*>(&Cb[((size_t)nh*64 + e)*4096 + tt]) = o;
      }
  } else {
    float* Cf = (float*)C;
    #pragma unroll
    for (int m=0;m<8;++m)
      #pragma unroll
      for (int n=0;n<4;++n)
        #pragma unroll
        for (int j=0;j<4;++j){
          int row = m0 + wr*128 + m*16 + lhi*4 + j;
          int col = c0 + wc*64 + n*16 + l15;
          Cf[(size_t)row*1024 + col] = acc[m][n][j];
        }
  }
}

// All 3 projection GEMMs in one launch: z=0 Q(mode0), z=1 K(mode0), z=2 V(mode2).
__global__ __launch_bounds__(512, 2) void gemm_qkv(const short* __restrict__ A0, const short* __restrict__ A1,
    const short* __restrict__ A2, const short* __restrict__ B0, const short* __restrict__ B1,
    const short* __restrict__ B2, short* __restrict__ C0, short* __restrict__ C1, short* __restrict__ C2){
  extern __shared__ short smem[];
  const int z = blockIdx.z;
  const short* A = z == 0 ? A0 : z == 1 ? A1 : A2;
  const short* B = z == 0 ? B0 : z == 1 ? B1 : B2;
  short* C       = z == 0 ? C0 : z == 1 ? C1 : C2;
  int m0, c0; remap_mc(blockIdx.x + 64*blockIdx.y, m0, c0);
  gemm_body(smem, A, B, (void*)C, z == 2 ? 2 : 0, m0, c0);
}

__global__ __launch_bounds__(512, 2) void gemm_wo(const short* __restrict__ A, const short* __restrict__ Bt,
                                                  float* __restrict__ C){
  extern __shared__ short smem[];
  int m0, c0; remap_mc(blockIdx.x + 64*blockIdx.y, m0, c0);
  gemm_body(smem, A, Bt, (void*)C, 1, m0, c0);
}

// ---------------- Stage A: delta^T[e][d] = sum_s vs[s][e]*sk[s][d] via MFMA ----------------
__global__ __launch_bounds__(256) void stageA(const short* __restrict__ kh, const short* __restrict__ vhT,
                                              short* __restrict__ delta_b, float* __restrict__ zd){
  const int seg = blockIdx.x, nh = blockIdx.y, tid = threadIdx.x;
  const int lane = tid & 63, w = tid >> 6;
  const int l15 = lane & 15, lhi = lane >> 4;
  __shared__ short skT[64*256];      // element (d,s) at byte ((d*256+s)*2) ^ (((d>>3)&7)<<4)
  const size_t thead = (size_t)nh*4096 + (size_t)seg*256;

  #pragma unroll
  for (int ch=0; ch<8; ++ch){
    int s  = ch*32 + (tid>>3);
    int lc = (tid&7)*8;
    bf16x8_t kv = *reinterpret_cast<const bf16x8_t*>(kh + (thead + s)*64 + lc);
    #pragma unroll
    for (int j=0;j<8;++j){
      float f = bf2f(kv[j]);
      short sv = f2bf((f > 0.f) ? (f + 1.f) : __expf(f));   // elu(k)+1
      int d = lc + j;
      int bo = ((d*256 + s) << 1) ^ (((d>>3)&7) << 4);
      *reinterpret_cast<short*>(reinterpret_cast<char*>(skT) + bo) = sv;
    }
  }
  __syncthreads();

  bf16x8_t ones;
  #pragma unroll
  for (int i=0;i<8;++i) ones[i] = (short)0x3F80;

  f32x4 dacc[4], zacc[4];
  #pragma unroll
  for (int jf=0;jf<4;++jf){ dacc[jf] = (f32x4){0.f,0.f,0.f,0.f}; zacc[jf] = (f32x4){0.f,0.f,0.f,0.f}; }

  #pragma unroll
  for (int ks=0; ks<8; ++ks){
    bf16x8_t av = *reinterpret_cast<const bf16x8_t*>(
        vhT + ((size_t)nh*64 + w*16 + l15)*4096 + (size_t)seg*256 + ks*32 + lhi*8);
    #pragma unroll
    for (int jf=0;jf<4;++jf){
      int d  = jf*16 + l15;
      int so = ks*32 + lhi*8;
      int bo = ((d*256 + so) << 1) ^ (((d>>3)&7) << 4);
      bf16x8_t bk = *reinterpret_cast<const bf16x8_t*>(reinterpret_cast<char*>(skT) + bo);
      dacc[jf] = mfma16(av, bk, dacc[jf]);
      if (w == 0) zacc[jf] = mfma16(ones, bk, zacc[jf]);
    }
  }

  short* dp = delta_b + (size_t)(seg*64 + nh)*4096;
  #pragma unroll
  for (int jf=0;jf<4;++jf)
    #pragma unroll
    for (int j=0;j<4;++j)
      dp[(w*16 + lhi*4 + j)*64 + jf*16 + l15] = f2bf(dacc[jf][j]);
  if (w == 0 && lhi == 0){
    #pragma unroll
    for (int jf=0;jf<4;++jf)
      zd[(size_t)(seg*64 + nh)*64 + jf*16 + l15] = zacc[jf][0];
  }
}

// ---------------- Stage B: exclusive prefix over the 16 segments (bf16 out) ----------------
__global__ __launch_bounds__(256) void stageB(const short* __restrict__ delta_b, const float* __restrict__ zd,
                                              short* __restrict__ mpre_b, float* __restrict__ zpre){
  const int c = blockIdx.x, nh = blockIdx.y, tid = threadIdx.x;
  const int idx = c*256 + tid;
  float acc = 0.f;
  for (int seg=0; seg<16; ++seg){
    size_t b = (size_t)(seg*64 + nh)*4096 + idx;
    mpre_b[b] = f2bf(acc);
    acc += bf2f(delta_b[b]);
  }
  if (c == 0 && tid < 64){
    float za = 0.f;
    for (int seg=0; seg<16; ++seg){
      size_t zb = (size_t)(seg*64 + nh)*64 + tid;
      zpre[zb] = za;
      za += zd[zb];
    }
  }
}

// ---------------- Stage C v5b: balanced lockstep causal attention + retrieval ----------------
// 1024 blocks (16 seg x 64 nh), 4 waves. Wave w owns 16-row frags at q-rows m*64+w*16, m=0..3
// (one frag per kt-tile). At kt, every wave computes frags m>=kt -> identical per-kt work.
// K/V block-shared in 2-deep LDS ring via global_load_lds (stage at kt top, wait at kt end).
__global__ __launch_bounds__(256) void stageC(const short* __restrict__ qh, const short* __restrict__ kh,
    const short* __restrict__ vhT, const short* __restrict__ mpre_b, const float* __restrict__ z_pre,
    const float* __restrict__ beta, short* __restrict__ seqs)
{
  const int seg  = blockIdx.x;
  const int nh   = blockIdx.y;
  const int tid = threadIdx.x;
  const int lane = tid & 63, w = tid >> 6;
  const int l15 = lane & 15, lhi = lane >> 4;

  __shared__ short Ks[2][4096];      // K tile [64 t'][8 slots x 8], slot = chunk ^ (r&7)
  __shared__ short Vs[2][4096];      // V^T tile [64 e][8 slots x 8], same swizzle
  __shared__ float zl[64];
  __shared__ short pl[4][64][72];    // per-wave P tile; frag m occupies rows [m*16, m*16+16)

  const size_t thead = (size_t)nh*4096 + (size_t)seg*256;

  const short* Ksrc[2]; const short* Vsrc[2];
  #pragma unroll
  for (int p=0;p<2;++p){
    int i = tid + 256*p, r = i >> 3, g = (i & 7) ^ (r & 7);
    Ksrc[p] = kh + (thead + r)*64 + g*8;                                    // + kt*4096
    Vsrc[p] = vhT + ((size_t)nh*64 + r)*4096 + (size_t)seg*256 + g*8;       // + kt*64
  }
  #define STAGE_KV(kt) { short* _kd = Ks[(kt)&1]; short* _vd = Vs[(kt)&1]; \
      gl_lds16(Ksrc[0] + (kt)*4096, _kd + tid*8); \
      gl_lds16(Ksrc[1] + (kt)*4096, _kd + 2048 + tid*8); \
      gl_lds16(Vsrc[0] + (kt)*64,  _vd + tid*8); \
      gl_lds16(Vsrc[1] + (kt)*64,  _vd + 2048 + tid*8); }

  if (tid < 64) zl[tid] = z_pre[(size_t)(seg*64 + nh)*64 + tid];

  // frag m covers q-rows m*64 + w*16 + [0,16)
  bf16x8_t aq[4][2];
  #pragma unroll
  for (int m=0;m<4;++m)
    #pragma unroll
    for (int ks=0;ks<2;++ks)
      aq[m][ks] = *reinterpret_cast<const bf16x8_t*>(qh + (thead + m*64 + w*16 + l15)*64 + ks*32 + lhi*8);

  STAGE_KV(0);
  asm volatile("s_waitcnt vmcnt(0)" ::: "memory");
  __syncthreads();

  const float bg = 1.f / (1.f + __expf(-beta[0]));
  const float scale = 0.125f;
  bf16x8_t ones;
  #pragma unroll
  for (int i=0;i<8;++i) ones[i] = (short)0x3F80;

  f32x4 o_acc[4][4], l_acc[4];
  #pragma unroll
  for (int m=0;m<4;++m){
    l_acc[m] = (f32x4){0.f,0.f,0.f,0.f};
    #pragma unroll
    for (int jf=0;jf<4;++jf) o_acc[m][jf] = (f32x4){0.f,0.f,0.f,0.f};
  }

  #pragma unroll
  for (int kt = 0; kt < 4; ++kt){
    const short* Kb = Ks[kt & 1];
    const short* Vb = Vs[kt & 1];
    if (kt < 3) STAGE_KV(kt+1);
    f32x4 s_acc[4][4];
    #pragma unroll
    for (int m=0;m<4;++m)
      if (m >= kt)
        #pragma unroll
        for (int jf=0;jf<4;++jf) s_acc[m][jf] = (f32x4){0.f,0.f,0.f,0.f};
    #pragma unroll
    for (int ks=0;ks<2;++ks){
      bf16x8_t bk[4];
      #pragma unroll
      for (int jf=0;jf<4;++jf){
        int r = jf*16 + l15;
        int sl = (ks*4 + lhi) ^ (r & 7);
        bk[jf] = *reinterpret_cast<const bf16x8_t*>(&Kb[r*64 + sl*8]);
      }
      #pragma unroll
      for (int m=0;m<4;++m)
        if (m >= kt)
          #pragma unroll
          for (int jf=0;jf<4;++jf)
            s_acc[m][jf] = mfma16(aq[m][ks], bk[jf], s_acc[m][jf]);
    }
    #pragma unroll
    for (int m=0;m<4;++m)
      if (m >= kt)
        #pragma unroll
        for (int jf=0;jf<4;++jf)
          #pragma unroll
          for (int j=0;j<4;++j){
            float vv = s_acc[m][jf][j] * scale;
            if (m == kt){
              int sr = w*16 + lhi*4 + j;     // local row within the 64-block
              int tc = jf*16 + l15;          // local col
              if (tc > sr) vv = -INFINITY;
            }
            float pv = __expf(vv);
            pl[w][m*16 + lhi*4 + j][jf*16 + l15] = f2bf(pv);
          }
    #pragma unroll
    for (int ks2=0;ks2<2;++ks2){
      bf16x8_t bv[4];
      #pragma unroll
      for (int jf=0;jf<4;++jf){
        int e = jf*16 + l15;
        int sl = (ks2*4 + lhi) ^ (e & 7);
        bv[jf] = *reinterpret_cast<const bf16x8_t*>(&Vb[e*64 + sl*8]);
      }
      #pragma unroll
      for (int m=0;m<4;++m)
        if (m >= kt){
          bf16x8_t ap = *reinterpret_cast<const bf16x8_t*>(&pl[w][m*16 + l15][ks2*32 + lhi*8]);
          l_acc[m] = mfma16(ap, ones, l_acc[m]);
          #pragma unroll
          for (int jf=0;jf<4;++jf)
            o_acc[m][jf] = mfma16(ap, bv[jf], o_acc[m][jf]);
        }
    }
    if (kt < 3){
      // race-fix tail: vmcnt drain + barrier + full pin (s_barrier is not an IR memory fence)
      asm volatile("s_waitcnt vmcnt(0)" ::: "memory");
      __builtin_amdgcn_s_barrier();
      __builtin_amdgcn_sched_barrier(0);
      asm volatile("" ::: "memory");
    }
  }
  #undef STAGE_KV

  // retrieval: num = (elu(q)+1) @ mem ; den = (elu(q)+1) . z
  bf16x8_t sq[4][2];
  #pragma unroll
  for (int m=0;m<4;++m)
    #pragma unroll
    for (int ks=0;ks<2;++ks)
      #pragma unroll
      for (int i=0;i<8;++i){
        float f = bf2f(aq[m][ks][i]);
        sq[m][ks][i] = f2bf((f > 0.f) ? (f + 1.f) : __expf(f));
      }
  bf16x8_t bz[2];
  #pragma unroll
  for (int ks=0;ks<2;++ks)
    #pragma unroll
    for (int i=0;i<8;++i) bz[ks][i] = f2bf(zl[ks*32 + lhi*8 + i]);

  const short* mpbase = mpre_b + (size_t)(seg*64 + nh)*4096;
  f32x4 n_acc[4][4], d_acc[4];
  #pragma unroll
  for (int m=0;m<4;++m){
    d_acc[m] = (f32x4){0.f,0.f,0.f,0.f};
    #pragma unroll
    for (int jf=0;jf<4;++jf) n_acc[m][jf] = (f32x4){0.f,0.f,0.f,0.f};
  }
  #pragma unroll
  for (int ks=0;ks<2;++ks){
    bf16x8_t bm[4];
    #pragma unroll
    for (int jf=0;jf<4;++jf)
      bm[jf] = *reinterpret_cast<const bf16x8_t*>(mpbase + (jf*16 + l15)*64 + ks*32 + lhi*8);
    #pragma unroll
    for (int m=0;m<4;++m){
      #pragma unroll
      for (int jf=0;jf<4;++jf) n_acc[m][jf] = mfma16(sq[m][ks], bm[jf], n_acc[m][jf]);
      d_acc[m] = mfma16(sq[m][ks], bz[ks], d_acc[m]);
    }
  }

  const int nb = nh >> 4, hh = nh & 15;
  #pragma unroll
  for (int m=0;m<4;++m)
    #pragma unroll
    for (int jf=0;jf<4;++jf)
      #pragma unroll
      for (int j=0;j<4;++j){
        float attn = o_acc[m][jf][j] / l_acc[m][j];
        float amem = n_acc[m][jf][j] / (d_acc[m][j] + 1e-6f);
        float ov = bg*amem + (1.f-bg)*attn;
        int srow = m*64 + w*16 + lhi*4 + j;
        seqs[((size_t)nb*4096 + (size_t)seg*256 + srow)*1024 + hh*64 + jf*16 + l15] = f2bf(ov);
      }
}

// ---------------- launch ----------------
extern "C" void kernel_launch(void* const* d_in, const int* in_sizes, int n_in,
                              void* d_out, int out_size, void* d_ws, size_t ws_size,
                              hipStream_t stream){
  (void)in_sizes; (void)n_in; (void)out_size; (void)ws_size;
  const float* q    = (const float*)d_in[0];
  const float* k    = (const float*)d_in[1];
  const float* v    = (const float*)d_in[2];
  const float* Wq   = (const float*)d_in[3];
  const float* Wk   = (const float*)d_in[4];
  const float* Wv   = (const float*)d_in[5];
  const float* Wo   = (const float*)d_in[6];
  const float* lnw  = (const float*)d_in[7];
  const float* lnb  = (const float*)d_in[8];
  const float* beta = (const float*)d_in[9];
  char* ws = (char*)d_ws;
  const size_t MB = 1024ull*1024ull;
  short* WqT    = (short*)(ws + 0*MB);
  short* WkT    = (short*)(ws + 2*MB);
  short* WvT    = (short*)(ws + 4*MB);
  short* WoT    = (short*)(ws + 6*MB);
  short* xn_v   = (short*)(ws + 8*MB);    // 32MB; reused as seqs after projections
  short* seqs   = xn_v;
  short* qh     = (short*)(ws + 40*MB);   // [nh][t][64]
  short* kh     = (short*)(ws + 72*MB);   // [nh][t][64]
  short* vhT    = (short*)(ws + 104*MB);  // [nh][e][t]
  short* delta_b= (short*)(ws + 136*MB);  // bf16 [16][64][e*64+d], 8MB
  float* zd     = (float*)(ws + 144*MB);  // 256KB
  short* mpre_b = (short*)(ws + 145*MB);  // bf16, 8MB
  float* zpre   = (float*)(ws + 153*MB);  // 256KB
  // d_out (16384*1024 f32 = 64MB) used as scratch for two bf16 LN outputs (2x32MB),
  // fully overwritten by gemm_wo at the end -> deterministic.
  short* xn_q   = (short*)d_out;
  short* xn_k   = (short*)d_out + 16384ull*1024ull;

  wcast4<<<dim3(16,16,4),256,0,stream>>>(Wq,Wk,Wv,Wo, WqT,WkT,WvT,WoT);
  ln3<<<dim3(16384,3),256,0,stream>>>(q,k,v, lnw,lnb, xn_q,xn_k,xn_v);

  const size_t lds_gemm = 131072;
  gemm_qkv<<<dim3(64,4,3),512,lds_gemm,stream>>>(xn_q,xn_k,xn_v, WqT,WkT,WvT, qh,kh,vhT);

  stageA<<<dim3(16,64),256,0,stream>>>(kh, vhT, delta_b, zd);
  stageB<<<dim3(16,64),256,0,stream>>>(delta_b, zd, mpre_b, zpre);
  stageC<<<dim3(16,64),256,0,stream>>>(qh, kh, vhT, mpre_b, zpre, beta, seqs);
  gemm_wo<<<dim3(64,4),512,lds_gemm,stream>>>(seqs, WoT, (float*)d_out);
}

// Round 19
// 288.755 us; speedup vs baseline: 1.0290x; 1.0152x over previous
//
#include <hip/hip_runtime.h>
#include <stdint.h>
#include <math.h>

// Infini-attention forward for MI355X (gfx950).
// Pipeline: prep (fused wcast4+ln3, independent work co-scheduled) ; gemm_qkv ; stageA ;
//           stageB ; stageC ; gemm_wo
// gemm v7: BK=64, 2-deep ring, half-tile staggered staging, counted vmcnt(4),
//   per-phase read|BAR|MFMA separation, XCD-chunked block remap, 8-slot XOR swizzle (0 conflicts).
// stageC v5b: lockstep kt, interleaved row ownership, race-fix barrier tails.
// xn_q/xn_k live in d_out (scratch until gemm_wo fully overwrites it -> deterministic).

typedef __attribute__((ext_vector_type(8))) short bf16x8_t;
typedef __attribute__((ext_vector_type(4))) short short4_t;
typedef __attribute__((ext_vector_type(4))) float f32x4;

__device__ __forceinline__ float bf2f(short s){
  union { unsigned u; float f; } v; v.u = ((unsigned)(unsigned short)s) << 16; return v.f;
}
__device__ __forceinline__ short f2bf(float f){
  union { float fl; unsigned u; } v; v.fl = f;
  unsigned r = v.u + 0x7FFFu + ((v.u >> 16) & 1u);   // RNE
  return (short)(unsigned short)(r >> 16);
}
__device__ __forceinline__ f32x4 mfma16(bf16x8_t a, bf16x8_t b, f32x4 c){
  return __builtin_amdgcn_mfma_f32_16x16x32_bf16(a, b, c, 0, 0, 0);
}
__device__ __forceinline__ void gl_lds16(const short* g, short* l){
  __builtin_amdgcn_global_load_lds((const __attribute__((address_space(1))) void*)g,
                                   (__attribute__((address_space(3))) void*)l, 16, 0, 0);
}
__device__ __forceinline__ void bar_pin(){
  __builtin_amdgcn_s_barrier();
  __builtin_amdgcn_sched_barrier(0);
  asm volatile("" ::: "memory");
}

// ---------------- prep: fused wcast (blocks 0..1023) + LN x3 (blocks 1024..50175) ----------
// Independent work items, disjoint outputs -> race-free; wcast's compute hides under LN's
// BW-bound stream.
__global__ __launch_bounds__(256) void prep(const float* __restrict__ xq, const float* __restrict__ xk,
    const float* __restrict__ xv, const float* __restrict__ gw, const float* __restrict__ gb,
    short* __restrict__ oq, short* __restrict__ ok, short* __restrict__ ov,
    const float* __restrict__ W0, const float* __restrict__ W1,
    const float* __restrict__ W2, const float* __restrict__ W3,
    short* __restrict__ T0, short* __restrict__ T1, short* __restrict__ T2, short* __restrict__ T3){
  __shared__ float tile[64][65];
  const int bid = blockIdx.x, tid = threadIdx.x;
  if (bid < 1024){
    // ---- wcast slice: z = bid>>8, by = (bid>>4)&15, bx = bid&15
    const int z = bid >> 8, by = (bid >> 4) & 15, bx = bid & 15;
    const float* W = z == 0 ? W0 : z == 1 ? W1 : z == 2 ? W2 : W3;
    short* Wt      = z == 0 ? T0 : z == 1 ? T1 : z == 2 ? T2 : T3;
    #pragma unroll
    for (int p=0;p<4;++p){
      int idx = p*256 + tid;
      int r = idx >> 4, c4 = (idx & 15) << 2;
      const float4 v = *reinterpret_cast<const float4*>(W + (size_t)(by*64 + r)*1024 + bx*64 + c4);
      tile[r][c4+0] = v.x; tile[r][c4+1] = v.y; tile[r][c4+2] = v.z; tile[r][c4+3] = v.w;
    }
    __syncthreads();
    #pragma unroll
    for (int p=0;p<4;++p){
      int idx = p*256 + tid;
      int r = idx >> 4, c4 = (idx & 15) << 2;
      short4_t o;
      o[0] = f2bf(tile[c4+0][r]); o[1] = f2bf(tile[c4+1][r]);
      o[2] = f2bf(tile[c4+2][r]); o[3] = f2bf(tile[c4+3][r]);
      *reinterpret_cast<short4_t*>(Wt + (size_t)(bx*64 + r)*1024 + by*64 + c4) = o;
    }
  } else {
    // ---- LN row: i = bid-1024; which = i>>14, row = i & 16383
    const int i = bid - 1024;
    const int which = i >> 14, row = i & 16383;
    const float* x = which == 0 ? xq : which == 1 ? xk : xv;
    short* out     = which == 0 ? oq : which == 1 ? ok : ov;
    float* red = &tile[0][0];
    const float4 v = *reinterpret_cast<const float4*>(x + (size_t)row*1024 + tid*4);
    float s  = v.x + v.y + v.z + v.w;
    float s2 = v.x*v.x + v.y*v.y + v.z*v.z + v.w*v.w;
    #pragma unroll
    for (int off = 1; off < 64; off <<= 1){
      s  += __shfl_xor(s,  off);
      s2 += __shfl_xor(s2, off);
    }
    if ((tid & 63) == 0){ red[tid>>6] = s; red[4 + (tid>>6)] = s2; }
    __syncthreads();
    s  = red[0] + red[1] + red[2] + red[3];
    s2 = red[4] + red[5] + red[6] + red[7];
    const float mu  = s * (1.0f/1024.0f);
    const float var = s2 * (1.0f/1024.0f) - mu*mu;
    const float rs  = rsqrtf(var + 1e-5f);
    const float4 wv = *reinterpret_cast<const float4*>(gw + tid*4);
    const float4 bv = *reinterpret_cast<const float4*>(gb + tid*4);
    short4_t o;
    o[0] = f2bf((v.x-mu)*rs*wv.x + bv.x);
    o[1] = f2bf((v.y-mu)*rs*wv.y + bv.y);
    o[2] = f2bf((v.z-mu)*rs*wv.z + bv.z);
    o[3] = f2bf((v.w-mu)*rs*wv.w + bv.w);
    *reinterpret_cast<short4_t*>(out + (size_t)row*1024 + tid*4) = o;
  }
}

// XCD-chunked remap of 256 (m,c) tiles: XCD k owns m-panels [8k,8k+8) x all 4 c-panels.
__device__ __forceinline__ void remap_mc(int n, int& m0, int& c0){
  int xcd = n & 7, idx = n >> 3;
  m0 = ((xcd << 3) + (idx & 7)) << 8;
  c0 = (idx >> 3) << 8;
}

// ---------------- GEMM body v7: C[16384][1024] = A @ Bt^T (bf16, K=1024) ----------------
__device__ __forceinline__ void gemm_body(short* smem, const short* __restrict__ A,
                                          const short* __restrict__ Bt, void* __restrict__ C,
                                          int mode, int m0, int c0){
  short* As = smem;            // 2 x [256 rows][8 slots][8 shorts]; half0 = rows 0-127
  short* Bs = smem + 32768;
  const int tid = threadIdx.x;
  const int lane = tid & 63, wid = tid >> 6;
  const int wr = wid >> 2, wc = wid & 3;
  const int l15 = lane & 15, lhi = lane >> 4;

  const short* Asrc[4]; const short* Bsrc[4];
  #pragma unroll
  for (int p=0;p<4;++p){
    int i = tid + 512*p;
    int r = i >> 3, g = (i & 7) ^ (r & 7);
    Asrc[p] = A  + (size_t)(m0 + r)*1024 + g*8;
    Bsrc[p] = Bt + (size_t)(c0 + r)*1024 + g*8;
  }

  f32x4 acc[8][4];
  #pragma unroll
  for (int m=0;m<8;++m)
    #pragma unroll
    for (int n=0;n<4;++n) acc[m][n] = (f32x4){0.f,0.f,0.f,0.f};

  #define STAGE_A0(t) { short* _d=&As[((t)&1)<<14]; int _k=(t)<<6; \
      gl_lds16(Asrc[0]+_k, _d+tid*8); gl_lds16(Asrc[1]+_k, _d+4096+tid*8); }
  #define STAGE_A1(t) { short* _d=&As[((t)&1)<<14]; int _k=(t)<<6; \
      gl_lds16(Asrc[2]+_k, _d+8192+tid*8); gl_lds16(Asrc[3]+_k, _d+12288+tid*8); }
  #define STAGE_B0(t) { short* _d=&Bs[((t)&1)<<14]; int _k=(t)<<6; \
      gl_lds16(Bsrc[0]+_k, _d+tid*8); gl_lds16(Bsrc[1]+_k, _d+4096+tid*8); }
  #define STAGE_B1(t) { short* _d=&Bs[((t)&1)<<14]; int _k=(t)<<6; \
      gl_lds16(Bsrc[2]+_k, _d+8192+tid*8); gl_lds16(Bsrc[3]+_k, _d+12288+tid*8); }

  STAGE_B0(0); STAGE_A0(0); STAGE_B1(0); STAGE_A1(0);
  STAGE_B0(1); STAGE_A0(1);
  asm volatile("s_waitcnt vmcnt(4)" ::: "memory");
  bar_pin();

  for (int t = 0; t < 16; ++t){
    const short* Ab = &As[(t & 1) << 14];
    const short* Bb = &Bs[(t & 1) << 14];
    bf16x8_t af[4][2], bfr[4][2];
    // ---- ph1: read A m0-3 + B n0-1 ; stage (t+1)B1 ; BAR ; MFMA m0-3 x n0-1
    #pragma unroll
    for (int m=0;m<4;++m){
      int r = wr*128 + m*16 + l15;
      #pragma unroll
      for (int ks=0;ks<2;++ks){
        int sl = (ks*4 + lhi) ^ (r & 7);
        af[m][ks] = *reinterpret_cast<const bf16x8_t*>(&Ab[r*64 + sl*8]);
      }
    }
    #pragma unroll
    for (int n=0;n<2;++n){
      int r = wc*64 + n*16 + l15;
      #pragma unroll
      for (int ks=0;ks<2;++ks){
        int sl = (ks*4 + lhi) ^ (r & 7);
        bfr[n][ks] = *reinterpret_cast<const bf16x8_t*>(&Bb[r*64 + sl*8]);
      }
    }
    if (t < 15) STAGE_B1(t+1);
    bar_pin();
    __builtin_amdgcn_s_setprio(1);
    #pragma unroll
    for (int m=0;m<4;++m)
      #pragma unroll
      for (int n=0;n<2;++n)
        #pragma unroll
        for (int ks=0;ks<2;++ks)
          acc[m][n] = mfma16(af[m][ks], bfr[n][ks], acc[m][n]);
    __builtin_amdgcn_s_setprio(0);
    // ---- ph2: read B n2-3 ; stage (t+1)A1 ; BAR ; MFMA m0-3 x n2-3
    #pragma unroll
    for (int n=2;n<4;++n){
      int r = wc*64 + n*16 + l15;
      #pragma unroll
      for (int ks=0;ks<2;++ks){
        int sl = (ks*4 + lhi) ^ (r & 7);
        bfr[n][ks] = *reinterpret_cast<const bf16x8_t*>(&Bb[r*64 + sl*8]);
      }
    }
    if (t < 15) STAGE_A1(t+1);
    bar_pin();
    __builtin_amdgcn_s_setprio(1);
    #pragma unroll
    for (int m=0;m<4;++m)
      #pragma unroll
      for (int n=2;n<4;++n)
        #pragma unroll
        for (int ks=0;ks<2;++ks)
          acc[m][n] = mfma16(af[m][ks], bfr[n][ks], acc[m][n]);
    __builtin_amdgcn_s_setprio(0);
    asm volatile("" ::: "memory");
    bar_pin();                        // B(t) consumed -> B0 region reusable
    // ---- ph3: read A m4-7 ; stage (t+2)B0 ; BAR ; MFMA m4-7 x n0-1
    #pragma unroll
    for (int m=0;m<4;++m){
      int r = wr*128 + 64 + m*16 + l15;
      #pragma unroll
      for (int ks=0;ks<2;++ks){
        int sl = (ks*4 + lhi) ^ (r & 7);
        af[m][ks] = *reinterpret_cast<const bf16x8_t*>(&Ab[r*64 + sl*8]);
      }
    }
    if (t < 14) STAGE_B0(t+2);
    bar_pin();
    __builtin_amdgcn_s_setprio(1);
    #pragma unroll
    for (int m=0;m<4;++m)
      #pragma unroll
      for (int n=0;n<2;++n)
        #pragma unroll
        for (int ks=0;ks<2;++ks)
          acc[4+m][n] = mfma16(af[m][ks], bfr[n][ks], acc[4+m][n]);
    __builtin_amdgcn_s_setprio(0);
    asm volatile("" ::: "memory");
    bar_pin();                        // A(t) consumed -> A0 region reusable
    // ---- ph4: stage (t+2)A0 ; MFMA m4-7 x n2-3 ; counted wait ; barrier
    if (t < 14) STAGE_A0(t+2);
    __builtin_amdgcn_s_setprio(1);
    #pragma unroll
    for (int m=0;m<4;++m)
      #pragma unroll
      for (int n=2;n<4;++n)
        #pragma unroll
        for (int ks=0;ks<2;++ks)
          acc[4+m][n] = mfma16(af[m][ks], bfr[n][ks], acc[4+m][n]);
    __builtin_amdgcn_s_setprio(0);
    if (t < 14)       { asm volatile("s_waitcnt vmcnt(4)" ::: "memory"); }
    else if (t == 14) { asm volatile("s_waitcnt vmcnt(0)" ::: "memory"); }
    if (t < 15) bar_pin();
  }
  #undef STAGE_A0
  #undef STAGE_A1
  #undef STAGE_B0
  #undef STAGE_B1

  if (mode == 0){
    short* Cb = (short*)C;
    #pragma unroll
    for (int m=0;m<8;++m)
      #pragma unroll
      for (int n=0;n<4;++n)
        #pragma unroll
        for (int j=0;j<4;++j){
          int row = m0 + wr*128 + m*16 + lhi*4 + j;
          int col = c0 + wc*64 + n*16 + l15;
          size_t oidx = ((size_t)((row>>12)*16 + (col>>6)) * 4096 + (size_t)(row & 4095)) * 64 + (col & 63);
          Cb[oidx] = f2bf(acc[m][n][j]);
        }
  } else if (mode == 2){
    short* Cb = (short*)C;
    #pragma unroll
    for (int m=0;m<8;++m)
      #pragma unroll
      for (int n=0;n<4;++n){
        int rowb = m0 + wr*128 + m*16 + lhi*4;
        int col  = c0 + wc*64 + n*16 + l15;
        int nh = ((rowb>>12)<<4) + (col>>6);
        int e  = col & 63;
        int tt = rowb & 4095;
        short4_t o;
        #pragma unroll
        for (int j=0;j<4;++j) o[j] = f2bf(acc[m][n][j]);
        *reinterpret_cast<short4_t*>(&Cb[((size_t)nh*64 + e)*4096 + tt]) = o;
      }
  } else {
    float* Cf = (float*)C;
    #pragma unroll
    for (int m=0;m<8;++m)
      #pragma unroll
      for (int n=0;n<4;++n)
        #pragma unroll
        for (int j=0;j<4;++j){
          int row = m0 + wr*128 + m*16 + lhi*4 + j;
          int col = c0 + wc*64 + n*16 + l15;
          Cf[(size_t)row*1024 + col] = acc[m][n][j];
        }
  }
}

// All 3 projection GEMMs in one launch: z=0 Q(mode0), z=1 K(mode0), z=2 V(mode2).
__global__ __launch_bounds__(512, 2) void gemm_qkv(const short* __restrict__ A0, const short* __restrict__ A1,
    const short* __restrict__ A2, const short* __restrict__ B0, const short* __restrict__ B1,
    const short* __restrict__ B2, short* __restrict__ C0, short* __restrict__ C1, short* __restrict__ C2){
  extern __shared__ short smem[];
  const int z = blockIdx.z;
  const short* A = z == 0 ? A0 : z == 1 ? A1 : A2;
  const short* B = z == 0 ? B0 : z == 1 ? B1 : B2;
  short* C       = z == 0 ? C0 : z == 1 ? C1 : C2;
  int m0, c0; remap_mc(blockIdx.x + 64*blockIdx.y, m0, c0);
  gemm_body(smem, A, B, (void*)C, z == 2 ? 2 : 0, m0, c0);
}

__global__ __launch_bounds__(512, 2) void gemm_wo(const short* __restrict__ A, const short* __restrict__ Bt,
                                                  float* __restrict__ C){
  extern __shared__ short smem[];
  int m0, c0; remap_mc(blockIdx.x + 64*blockIdx.y, m0, c0);
  gemm_body(smem, A, Bt, (void*)C, 1, m0, c0);
}

// ---------------- Stage A: delta^T[e][d] = sum_s vs[s][e]*sk[s][d] via MFMA ----------------
__global__ __launch_bounds__(256) void stageA(const short* __restrict__ kh, const short* __restrict__ vhT,
                                              short* __restrict__ delta_b, float* __restrict__ zd){
  const int seg = blockIdx.x, nh = blockIdx.y, tid = threadIdx.x;
  const int lane = tid & 63, w = tid >> 6;
  const int l15 = lane & 15, lhi = lane >> 4;
  __shared__ short skT[64*256];      // element (d,s) at byte ((d*256+s)*2) ^ (((d>>3)&7)<<4)
  const size_t thead = (size_t)nh*4096 + (size_t)seg*256;

  #pragma unroll
  for (int ch=0; ch<8; ++ch){
    int s  = ch*32 + (tid>>3);
    int lc = (tid&7)*8;
    bf16x8_t kv = *reinterpret_cast<const bf16x8_t*>(kh + (thead + s)*64 + lc);
    #pragma unroll
    for (int j=0;j<8;++j){
      float f = bf2f(kv[j]);
      short sv = f2bf((f > 0.f) ? (f + 1.f) : __expf(f));   // elu(k)+1
      int d = lc + j;
      int bo = ((d*256 + s) << 1) ^ (((d>>3)&7) << 4);
      *reinterpret_cast<short*>(reinterpret_cast<char*>(skT) + bo) = sv;
    }
  }
  __syncthreads();

  bf16x8_t ones;
  #pragma unroll
  for (int i=0;i<8;++i) ones[i] = (short)0x3F80;

  f32x4 dacc[4], zacc[4];
  #pragma unroll
  for (int jf=0;jf<4;++jf){ dacc[jf] = (f32x4){0.f,0.f,0.f,0.f}; zacc[jf] = (f32x4){0.f,0.f,0.f,0.f}; }

  #pragma unroll
  for (int ks=0; ks<8; ++ks){
    bf16x8_t av = *reinterpret_cast<const bf16x8_t*>(
        vhT + ((size_t)nh*64 + w*16 + l15)*4096 + (size_t)seg*256 + ks*32 + lhi*8);
    #pragma unroll
    for (int jf=0;jf<4;++jf){
      int d  = jf*16 + l15;
      int so = ks*32 + lhi*8;
      int bo = ((d*256 + so) << 1) ^ (((d>>3)&7) << 4);
      bf16x8_t bk = *reinterpret_cast<const bf16x8_t*>(reinterpret_cast<char*>(skT) + bo);
      dacc[jf] = mfma16(av, bk, dacc[jf]);
      if (w == 0) zacc[jf] = mfma16(ones, bk, zacc[jf]);
    }
  }

  short* dp = delta_b + (size_t)(seg*64 + nh)*4096;
  #pragma unroll
  for (int jf=0;jf<4;++jf)
    #pragma unroll
    for (int j=0;j<4;++j)
      dp[(w*16 + lhi*4 + j)*64 + jf*16 + l15] = f2bf(dacc[jf][j]);
  if (w == 0 && lhi == 0){
    #pragma unroll
    for (int jf=0;jf<4;++jf)
      zd[(size_t)(seg*64 + nh)*64 + jf*16 + l15] = zacc[jf][0];
  }
}

// ---------------- Stage B: exclusive prefix over the 16 segments (bf16 out) ----------------
__global__ __launch_bounds__(256) void stageB(const short* __restrict__ delta_b, const float* __restrict__ zd,
                                              short* __restrict__ mpre_b, float* __restrict__ zpre){
  const int c = blockIdx.x, nh = blockIdx.y, tid = threadIdx.x;
  const int idx = c*256 + tid;
  float acc = 0.f;
  for (int seg=0; seg<16; ++seg){
    size_t b = (size_t)(seg*64 + nh)*4096 + idx;
    mpre_b[b] = f2bf(acc);
    acc += bf2f(delta_b[b]);
  }
  if (c == 0 && tid < 64){
    float za = 0.f;
    for (int seg=0; seg<16; ++seg){
      size_t zb = (size_t)(seg*64 + nh)*64 + tid;
      zpre[zb] = za;
      za += zd[zb];
    }
  }
}

// ---------------- Stage C v5b: balanced lockstep causal attention + retrieval ----------------
__global__ __launch_bounds__(256) void stageC(const short* __restrict__ qh, const short* __restrict__ kh,
    const short* __restrict__ vhT, const short* __restrict__ mpre_b, const float* __restrict__ z_pre,
    const float* __restrict__ beta, short* __restrict__ seqs)
{
  const int seg  = blockIdx.x;
  const int nh   = blockIdx.y;
  const int tid = threadIdx.x;
  const int lane = tid & 63, w = tid >> 6;
  const int l15 = lane & 15, lhi = lane >> 4;

  __shared__ short Ks[2][4096];      // K tile [64 t'][8 slots x 8], slot = chunk ^ (r&7)
  __shared__ short Vs[2][4096];      // V^T tile [64 e][8 slots x 8], same swizzle
  __shared__ float zl[64];
  __shared__ short pl[4][64][72];    // per-wave P tile; frag m occupies rows [m*16, m*16+16)

  const size_t thead = (size_t)nh*4096 + (size_t)seg*256;

  const short* Ksrc[2]; const short* Vsrc[2];
  #pragma unroll
  for (int p=0;p<2;++p){
    int i = tid + 256*p, r = i >> 3, g = (i & 7) ^ (r & 7);
    Ksrc[p] = kh + (thead + r)*64 + g*8;                                    // + kt*4096
    Vsrc[p] = vhT + ((size_t)nh*64 + r)*4096 + (size_t)seg*256 + g*8;       // + kt*64
  }
  #define STAGE_KV(kt) { short* _kd = Ks[(kt)&1]; short* _vd = Vs[(kt)&1]; \
      gl_lds16(Ksrc[0] + (kt)*4096, _kd + tid*8); \
      gl_lds16(Ksrc[1] + (kt)*4096, _kd + 2048 + tid*8); \
      gl_lds16(Vsrc[0] + (kt)*64,  _vd + tid*8); \
      gl_lds16(Vsrc[1] + (kt)*64,  _vd + 2048 + tid*8); }

  if (tid < 64) zl[tid] = z_pre[(size_t)(seg*64 + nh)*64 + tid];

  // frag m covers q-rows m*64 + w*16 + [0,16)
  bf16x8_t aq[4][2];
  #pragma unroll
  for (int m=0;m<4;++m)
    #pragma unroll
    for (int ks=0;ks<2;++ks)
      aq[m][ks] = *reinterpret_cast<const bf16x8_t*>(qh + (thead + m*64 + w*16 + l15)*64 + ks*32 + lhi*8);

  STAGE_KV(0);
  asm volatile("s_waitcnt vmcnt(0)" ::: "memory");
  __syncthreads();

  const float bg = 1.f / (1.f + __expf(-beta[0]));
  const float scale = 0.125f;
  bf16x8_t ones;
  #pragma unroll
  for (int i=0;i<8;++i) ones[i] = (short)0x3F80;

  f32x4 o_acc[4][4], l_acc[4];
  #pragma unroll
  for (int m=0;m<4;++m){
    l_acc[m] = (f32x4){0.f,0.f,0.f,0.f};
    #pragma unroll
    for (int jf=0;jf<4;++jf) o_acc[m][jf] = (f32x4){0.f,0.f,0.f,0.f};
  }

  #pragma unroll
  for (int kt = 0; kt < 4; ++kt){
    const short* Kb = Ks[kt & 1];
    const short* Vb = Vs[kt & 1];
    if (kt < 3) STAGE_KV(kt+1);
    f32x4 s_acc[4][4];
    #pragma unroll
    for (int m=0;m<4;++m)
      if (m >= kt)
        #pragma unroll
        for (int jf=0;jf<4;++jf) s_acc[m][jf] = (f32x4){0.f,0.f,0.f,0.f};
    #pragma unroll
    for (int ks=0;ks<2;++ks){
      bf16x8_t bk[4];
      #pragma unroll
      for (int jf=0;jf<4;++jf){
        int r = jf*16 + l15;
        int sl = (ks*4 + lhi) ^ (r & 7);
        bk[jf] = *reinterpret_cast<const bf16x8_t*>(&Kb[r*64 + sl*8]);
      }
      #pragma unroll
      for (int m=0;m<4;++m)
        if (m >= kt)
          #pragma unroll
          for (int jf=0;jf<4;++jf)
            s_acc[m][jf] = mfma16(aq[m][ks], bk[jf], s_acc[m][jf]);
    }
    #pragma unroll
    for (int m=0;m<4;++m)
      if (m >= kt)
        #pragma unroll
        for (int jf=0;jf<4;++jf)
          #pragma unroll
          for (int j=0;j<4;++j){
            float vv = s_acc[m][jf][j] * scale;
            if (m == kt){
              int sr = w*16 + lhi*4 + j;     // local row within the 64-block
              int tc = jf*16 + l15;          // local col
              if (tc > sr) vv = -INFINITY;
            }
            float pv = __expf(vv);
            pl[w][m*16 + lhi*4 + j][jf*16 + l15] = f2bf(pv);
          }
    #pragma unroll
    for (int ks2=0;ks2<2;++ks2){
      bf16x8_t bv[4];
      #pragma unroll
      for (int jf=0;jf<4;++jf){
        int e = jf*16 + l15;
        int sl = (ks2*4 + lhi) ^ (e & 7);
        bv[jf] = *reinterpret_cast<const bf16x8_t*>(&Vb[e*64 + sl*8]);
      }
      #pragma unroll
      for (int m=0;m<4;++m)
        if (m >= kt){
          bf16x8_t ap = *reinterpret_cast<const bf16x8_t*>(&pl[w][m*16 + l15][ks2*32 + lhi*8]);
          l_acc[m] = mfma16(ap, ones, l_acc[m]);
          #pragma unroll
          for (int jf=0;jf<4;++jf)
            o_acc[m][jf] = mfma16(ap, bv[jf], o_acc[m][jf]);
        }
    }
    if (kt < 3){
      // race-fix tail: vmcnt drain + barrier + full pin (s_barrier is not an IR memory fence)
      asm volatile("s_waitcnt vmcnt(0)" ::: "memory");
      __builtin_amdgcn_s_barrier();
      __builtin_amdgcn_sched_barrier(0);
      asm volatile("" ::: "memory");
    }
  }
  #undef STAGE_KV

  // retrieval: num = (elu(q)+1) @ mem ; den = (elu(q)+1) . z
  bf16x8_t sq[4][2];
  #pragma unroll
  for (int m=0;m<4;++m)
    #pragma unroll
    for (int ks=0;ks<2;++ks)
      #pragma unroll
      for (int i=0;i<8;++i){
        float f = bf2f(aq[m][ks][i]);
        sq[m][ks][i] = f2bf((f > 0.f) ? (f + 1.f) : __expf(f));
      }
  bf16x8_t bz[2];
  #pragma unroll
  for (int ks=0;ks<2;++ks)
    #pragma unroll
    for (int i=0;i<8;++i) bz[ks][i] = f2bf(zl[ks*32 + lhi*8 + i]);

  const short* mpbase = mpre_b + (size_t)(seg*64 + nh)*4096;
  f32x4 n_acc[4][4], d_acc[4];
  #pragma unroll
  for (int m=0;m<4;++m){
    d_acc[m] = (f32x4){0.f,0.f,0.f,0.f};
    #pragma unroll
    for (int jf=0;jf<4;++jf) n_acc[m][jf] = (f32x4){0.f,0.f,0.f,0.f};
  }
  #pragma unroll
  for (int ks=0;ks<2;++ks){
    bf16x8_t bm[4];
    #pragma unroll
    for (int jf=0;jf<4;++jf)
      bm[jf] = *reinterpret_cast<const bf16x8_t*>(mpbase + (jf*16 + l15)*64 + ks*32 + lhi*8);
    #pragma unroll
    for (int m=0;m<4;++m){
      #pragma unroll
      for (int jf=0;jf<4;++jf) n_acc[m][jf] = mfma16(sq[m][ks], bm[jf], n_acc[m][jf]);
      d_acc[m] = mfma16(sq[m][ks], bz[ks], d_acc[m]);
    }
  }

  const int nb = nh >> 4, hh = nh & 15;
  #pragma unroll
  for (int m=0;m<4;++m)
    #pragma unroll
    for (int jf=0;jf<4;++jf)
      #pragma unroll
      for (int j=0;j<4;++j){
        float attn = o_acc[m][jf][j] / l_acc[m][j];
        float amem = n_acc[m][jf][j] / (d_acc[m][j] + 1e-6f);
        float ov = bg*amem + (1.f-bg)*attn;
        int srow = m*64 + w*16 + lhi*4 + j;
        seqs[((size_t)nb*4096 + (size_t)seg*256 + srow)*1024 + hh*64 + jf*16 + l15] = f2bf(ov);
      }
}

// ---------------- launch ----------------
extern "C" void kernel_launch(void* const* d_in, const int* in_sizes, int n_in,
                              void* d_out, int out_size, void* d_ws, size_t ws_size,
                              hipStream_t stream){
  (void)in_sizes; (void)n_in; (void)out_size; (void)ws_size;
  const float* q    = (const float*)d_in[0];
  const float* k    = (const float*)d_in[1];
  const float* v    = (const float*)d_in[2];
  const float* Wq   = (const float*)d_in[3];
  const float* Wk   = (const float*)d_in[4];
  const float* Wv   = (const float*)d_in[5];
  const float* Wo   = (const float*)d_in[6];
  const float* lnw  = (const float*)d_in[7];
  const float* lnb  = (const float*)d_in[8];
  const float* beta = (const float*)d_in[9];
  char* ws = (char*)d_ws;
  const size_t MB = 1024ull*1024ull;
  short* WqT    = (short*)(ws + 0*MB);
  short* WkT    = (short*)(ws + 2*MB);
  short* WvT    = (short*)(ws + 4*MB);
  short* WoT    = (short*)(ws + 6*MB);
  short* xn_v   = (short*)(ws + 8*MB);    // 32MB; reused as seqs after projections
  short* seqs   = xn_v;
  short* qh     = (short*)(ws + 40*MB);   // [nh][t][64]
  short* kh     = (short*)(ws + 72*MB);   // [nh][t][64]
  short* vhT    = (short*)(ws + 104*MB);  // [nh][e][t]
  short* delta_b= (short*)(ws + 136*MB);  // bf16 [16][64][e*64+d], 8MB
  float* zd     = (float*)(ws + 144*MB);  // 256KB
  short* mpre_b = (short*)(ws + 145*MB);  // bf16, 8MB
  float* zpre   = (float*)(ws + 153*MB);  // 256KB
  // d_out (16384*1024 f32 = 64MB) used as scratch for two bf16 LN outputs (2x32MB),
  // fully overwritten by gemm_wo at the end -> deterministic.
  short* xn_q   = (short*)d_out;
  short* xn_k   = (short*)d_out + 16384ull*1024ull;

  // fused wcast(1024 blocks) + LN x3 (49152 blocks)
  prep<<<50176,256,0,stream>>>(q,k,v, lnw,lnb, xn_q,xn_k,xn_v,
                               Wq,Wk,Wv,Wo, WqT,WkT,WvT,WoT);

  const size_t lds_gemm = 131072;
  gemm_qkv<<<dim3(64,4,3),512,lds_gemm,stream>>>(xn_q,xn_k,xn_v, WqT,WkT,WvT, qh,kh,vhT);

  stageA<<<dim3(16,64),256,0,stream>>>(kh, vhT, delta_b, zd);
  stageB<<<dim3(16,64),256,0,stream>>>(delta_b, zd, mpre_b, zpre);
  stageC<<<dim3(16,64),256,0,stream>>>(qh, kh, vhT, mpre_b, zpre, beta, seqs);
  gemm_wo<<<dim3(64,4),512,lds_gemm,stream>>>(seqs, WoT, (float*)d_out);
}